// Round 8
// baseline (59.860 us; speedup 1.0000x reference)
//
#include <hip/hip_runtime.h>

// Problem constants (from reference): N=8192, D=1024, E=8192, K=16.
#define NROWS 8192
#define DDIM  1024
#define EEDGE 8192
#define KNB   16
#define ROWS_PER_BLK 16
#define WBLK (NROWS / ROWS_PER_BLK)   // 512 writer blocks (2/CU, fill-like shape)

typedef float f32x4 __attribute__((ext_vector_type(4)));

// Kernel 1: s1[i] = sent[i,:]·w1 + b ; s2[i] = sent[i,:]·w2
// One 64-lane wave per row; 4 waves (256 threads) per block.
__global__ __launch_bounds__(256) void dots_kernel(const float* __restrict__ sent,
                                                   const float* __restrict__ W,
                                                   const float* __restrict__ b,
                                                   float* __restrict__ s1,
                                                   float* __restrict__ s2) {
    int gwave = (blockIdx.x * 256 + threadIdx.x) >> 6;   // global wave id = row
    int lane  = threadIdx.x & 63;
    if (gwave >= NROWS) return;
    const f32x4* row = reinterpret_cast<const f32x4*>(sent + (size_t)gwave * DDIM);
    const f32x4* w1v = reinterpret_cast<const f32x4*>(W);
    const f32x4* w2v = reinterpret_cast<const f32x4*>(W + DDIM);
    float a1 = 0.f, a2 = 0.f;
#pragma unroll
    for (int it = 0; it < 4; ++it) {
        int idx = lane + it * 64;          // f32x4 index within row (256 total)
        f32x4 r  = row[idx];
        f32x4 x1 = w1v[idx];
        f32x4 x2 = w2v[idx];
        a1 += r.x * x1.x + r.y * x1.y + r.z * x1.z + r.w * x1.w;
        a2 += r.x * x2.x + r.y * x2.y + r.z * x2.z + r.w * x2.w;
    }
#pragma unroll
    for (int off = 32; off > 0; off >>= 1) {
        a1 += __shfl_xor(a1, off, 64);
        a2 += __shfl_xor(a2, off, 64);
    }
    if (lane == 0) {
        s1[gwave] = a1 + b[0];   // fold bias into s1
        s2[gwave] = a2;
    }
}

// Kernel 2: each block owns 16 rows -> 128 independent plain stores per
// thread (fill-kernel-like: low occupancy, long store runs). s2 slice held
// in 8 f32x4 registers; threads 0..239 also produce the pair outputs.
__global__ __launch_bounds__(256) void write_kernel(const int* __restrict__ edge,
                                                    const float* __restrict__ s1,
                                                    const float* __restrict__ s2,
                                                    float* __restrict__ pair,
                                                    float* __restrict__ alls) {
    const int t        = threadIdx.x;
    const int base_row = blockIdx.x * ROWS_PER_BLK;

    if (t < ROWS_PER_BLK * (KNB - 1)) {    // 240 pair outputs for this block
        int e = base_row + t / (KNB - 1);
        int k = t % (KNB - 1);
        int c = edge[e * KNB];
        int n = edge[e * KNB + 1 + k];
        pair[e * (KNB - 1) + k] = s1[c] + s2[n];
    }

    const f32x4* s2v = reinterpret_cast<const f32x4*>(s2);
    f32x4 vv[8];
#pragma unroll
    for (int it = 0; it < 8; ++it)
        vv[it] = s2v[t + it * 256];        // thread's s2 slice, loaded once

    float v1[ROWS_PER_BLK];
#pragma unroll
    for (int r = 0; r < ROWS_PER_BLK; ++r)
        v1[r] = s1[base_row + r];          // b already folded into s1

    float* o0 = alls + (size_t)base_row * NROWS;
#pragma unroll
    for (int it = 0; it < 8; ++it) {
#pragma unroll
        for (int r = 0; r < ROWS_PER_BLK; ++r) {
            f32x4 v = vv[it] + v1[r];      // ext_vector scalar broadcast
            f32x4* o = reinterpret_cast<f32x4*>(o0 + (size_t)r * NROWS);
            o[t + it * 256] = v;           // plain store, long independent run
        }
    }
}

extern "C" void kernel_launch(void* const* d_in, const int* in_sizes, int n_in,
                              void* d_out, int out_size, void* d_ws, size_t ws_size,
                              hipStream_t stream) {
    const float* sent = (const float*)d_in[0];   // (N, D) f32
    const float* W    = (const float*)d_in[1];   // (2D,)  f32
    const float* b    = (const float*)d_in[2];   // (1,)   f32
    const int*   edge = (const int*)  d_in[3];   // (E, K) i32

    float* out  = (float*)d_out;
    float* pair = out;                              // E*(K-1) floats
    float* alls = out + (size_t)EEDGE * (KNB - 1);  // N*N floats

    float* s1 = (float*)d_ws;        // N floats
    float* s2 = s1 + NROWS;          // N floats (64 KiB of d_ws total)

    dots_kernel<<<NROWS / 4, 256, 0, stream>>>(sent, W, b, s1, s2);
    write_kernel<<<WBLK, 256, 0, stream>>>(edge, s1, s2, pair, alls);
}

// Round 9
// 57.333 us; speedup vs baseline: 1.0441x; 1.0441x over previous
//
#include <hip/hip_runtime.h>

// Problem constants (from reference): N=8192, D=1024, E=8192, K=16.
#define NROWS 8192
#define DDIM  1024
#define EEDGE 8192
#define KNB   16

#define GSBLK 512                       // writer blocks (grid-stride)
#define TOTV  (NROWS * (NROWS / 4))     // 16.8M f32x4 elements of all_score
#define NITER (TOTV / (GSBLK * 256))    // 128 f32x4 stores per thread

typedef float f32x4 __attribute__((ext_vector_type(4)));

// Kernel 1: s1[i] = sent[i,:]·w1 + b ; s2[i] = sent[i,:]·w2
// One 64-lane wave per row; 4 waves (256 threads) per block.
__global__ __launch_bounds__(256) void dots_kernel(const float* __restrict__ sent,
                                                   const float* __restrict__ W,
                                                   const float* __restrict__ b,
                                                   float* __restrict__ s1,
                                                   float* __restrict__ s2) {
    int gwave = (blockIdx.x * 256 + threadIdx.x) >> 6;   // global wave id = row
    int lane  = threadIdx.x & 63;
    if (gwave >= NROWS) return;
    const f32x4* row = reinterpret_cast<const f32x4*>(sent + (size_t)gwave * DDIM);
    const f32x4* w1v = reinterpret_cast<const f32x4*>(W);
    const f32x4* w2v = reinterpret_cast<const f32x4*>(W + DDIM);
    float a1 = 0.f, a2 = 0.f;
#pragma unroll
    for (int it = 0; it < 4; ++it) {
        int idx = lane + it * 64;          // f32x4 index within row (256 total)
        f32x4 r  = row[idx];
        f32x4 x1 = w1v[idx];
        f32x4 x2 = w2v[idx];
        a1 += r.x * x1.x + r.y * x1.y + r.z * x1.z + r.w * x1.w;
        a2 += r.x * x2.x + r.y * x2.y + r.z * x2.z + r.w * x2.w;
    }
#pragma unroll
    for (int off = 32; off > 0; off >>= 1) {
        a1 += __shfl_xor(a1, off, 64);
        a2 += __shfl_xor(a2, off, 64);
    }
    if (lane == 0) {
        s1[gwave] = a1 + b[0];   // fold bias into s1
        s2[gwave] = a2;
    }
}

// Kernel 2: grid-stride linear sweep over all_score (fill-kernel address
// pattern: whole grid writes a dense contiguous segment per iteration,
// marching monotonically). Stride is a multiple of 2048 f32x4, so each
// thread's column (g & 2047) is CONSTANT -> its s2 value lives in one
// register; row (g >> 11) is wave-uniform -> s1 load is a broadcast L1 hit.
// Inner loop = broadcast load + 4 adds + dwordx4 store, all independent.
__global__ __launch_bounds__(256) void write_kernel(const int* __restrict__ edge,
                                                    const float* __restrict__ s1,
                                                    const float* __restrict__ s2,
                                                    float* __restrict__ pair,
                                                    float* __restrict__ alls) {
    const int t  = threadIdx.x;
    const int gt = blockIdx.x * 256 + t;          // 0 .. GSBLK*256-1

    // pair outputs: 16 edges per block (8192/512), 240 elements
    if (t < 16 * (KNB - 1)) {
        int e = blockIdx.x * 16 + t / (KNB - 1);
        int k = t % (KNB - 1);
        int c = edge[e * KNB];
        int n = edge[e * KNB + 1 + k];
        pair[e * (KNB - 1) + k] = s1[c] + s2[n];
    }

    const f32x4* s2v = reinterpret_cast<const f32x4*>(s2);
    f32x4* ov = reinterpret_cast<f32x4*>(alls);

    const float v2x4[4] = { s2v[gt & 2047].x, s2v[gt & 2047].y,
                            s2v[gt & 2047].z, s2v[gt & 2047].w };
    f32x4 v2;
    v2.x = v2x4[0]; v2.y = v2x4[1]; v2.z = v2x4[2]; v2.w = v2x4[3];

#pragma unroll
    for (int it = 0; it < NITER; ++it) {
        int g   = gt + it * (GSBLK * 256);        // stride = 131072 f32x4
        int row = g >> 11;                        // wave-uniform
        f32x4 v = v2 + s1[row];                   // broadcast + 4 adds
        ov[g] = v;                                // plain dwordx4 store
    }
}

extern "C" void kernel_launch(void* const* d_in, const int* in_sizes, int n_in,
                              void* d_out, int out_size, void* d_ws, size_t ws_size,
                              hipStream_t stream) {
    const float* sent = (const float*)d_in[0];   // (N, D) f32
    const float* W    = (const float*)d_in[1];   // (2D,)  f32
    const float* b    = (const float*)d_in[2];   // (1,)   f32
    const int*   edge = (const int*)  d_in[3];   // (E, K) i32

    float* out  = (float*)d_out;
    float* pair = out;                              // E*(K-1) floats
    float* alls = out + (size_t)EEDGE * (KNB - 1);  // N*N floats

    float* s1 = (float*)d_ws;        // N floats
    float* s2 = s1 + NROWS;          // N floats (64 KiB of d_ws total)

    dots_kernel<<<NROWS / 4, 256, 0, stream>>>(sent, W, b, s1, s2);
    write_kernel<<<GSBLK, 256, 0, stream>>>(edge, s1, s2, pair, alls);
}